// Round 7
// baseline (141.710 us; speedup 1.0000x reference)
//
#include <hip/hip_runtime.h>
#include <math.h>

// loss = -sum_ij d1[i,j] * log(d2[i,j] + 1e-5), fp32 in, scalar fp32 out.
//
// Session ledger (loss-kernel us): R0 43.4 | R2 44.9 (8-deep VGPR pipe: null)
//   | R3 37.7 (sc0 sc1 nt) | R4 31 (split read-return paths: d2 LDS-direct,
//   d1 VGPR) | R5 39.6 (aux=19 bypass on LDS path: BAD) | R6 34 (aux=0,
//   write-once slots: policy recovered 5.6, structure cost +3 vs ring).
// Confirmed mechanisms:
//  - Both inputs ~50% dirty-L3-resident (FETCH == half of demand, always).
//  - Allocate-on-read evicts dirty lines -> concurrent HBM writeback storm
//    (WRITE_SIZE ~64 MB on a read-only kernel). Fixed by no-allocate.
//  - SC0/SC1 bypass skips the L3 lookup -> loses the ~50% dirty hits
//    (R5/R6 de-confound, -5.6 us).
//  - Ring-4 @ 16 KB/block (8 blocks/CU, 32 waves) beats write-once-8 @
//    32 KB (5 blocks/CU): TLP > per-wave depth (also R2).
//  - Reduction tree FROZEN (absmax 0.0): thread t owns t + p*STRIDE p=0..7,
//    acc by component, wave shuffle, 4-wave LDS combine, partials[blk].
// R7: R4 structure byte-exact; policy -> NT-ONLY on BOTH streams
//     (d1: "nt", no sc0/sc1; d2: aux=2 = NT bit). NT = lookup still hits
//     dirty L3 lines, but misses don't allocate (no eviction cascade).
//     Both policy benefits simultaneously.

#define EPS 1e-5f
#define BLOCK 256
#define GRID 2048                 // GRID*BLOCK*8 == n4 exactly
#define STRIDE (GRID * BLOCK)     // float4 stride between a thread's windows

typedef float f4v __attribute__((ext_vector_type(4)));

#define AS1 __attribute__((address_space(1)))
#define AS3 __attribute__((address_space(3)))

#define CPOL_NT_ONLY 2   // NT bit only: no-allocate, lookup preserved

// d1 load on the VGPR-return path: NT only (keep L3 hits, don't allocate).
#define LOADX(X, PA)                                                 \
    asm volatile("global_load_dwordx4 %0, %1, off nt"                \
                 : "=&v"(X) : "v"(PA) : "memory")

// Hand-counted vmem wait + scheduling fence (rule #18).
#define WAITV(N)                                              \
    do {                                                      \
        asm volatile("s_waitcnt vmcnt(" #N ")" ::: "memory"); \
        __builtin_amdgcn_sched_barrier(0);                    \
    } while (0)

// Drain LDS reads before ring-slot reuse.
#define WAITLGKM()                                              \
    do {                                                        \
        asm volatile("s_waitcnt lgkmcnt(0)" ::: "memory");      \
        __builtin_amdgcn_sched_barrier(0);                      \
    } while (0)

// Same element->acc mapping and fma contraction as the baseline.
#define CP(X, Y)                                              \
    do {                                                      \
        acc0 = fmaf((X).x, __logf((Y).x + EPS), acc0);        \
        acc1 = fmaf((X).y, __logf((Y).y + EPS), acc1);        \
        acc2 = fmaf((X).z, __logf((Y).z + EPS), acc2);        \
        acc3 = fmaf((X).w, __logf((Y).w + EPS), acc3);        \
    } while (0)

__global__ __launch_bounds__(BLOCK) void cep_loss_kernel(
        const f4v* __restrict__ d1,
        const f4v* __restrict__ d2,
        float* __restrict__ partials) {
    // 4-deep ring: 4 x 256 x 16B = 16 KB/block -> 8 blocks/CU = 32 waves/CU.
    __shared__ f4v sB[4][BLOCK];

    const int tid = blockIdx.x * BLOCK + threadIdx.x;
    const int wb  = threadIdx.x & ~63;   // wave-uniform LDS slot base
    const f4v* pa = d1 + tid;
    const f4v* pb = d2 + tid;

    float acc0 = 0.0f, acc1 = 0.0f, acc2 = 0.0f, acc3 = 0.0f;
    f4v x0, x1, x2, x3, x4, x5, x6, x7;

    // One stage: d2 -> LDS-direct with NT-only policy (hit dirty L3, no
    // allocate); d1 -> VGPR path with NT-only.
#define ISSUE(BUF, X)                                                    \
    do {                                                                 \
        __builtin_amdgcn_global_load_lds(                                \
            (const AS1 void*)pb, (AS3 void*)&sB[BUF][wb], 16, 0,         \
            CPOL_NT_ONLY);                                               \
        LOADX(X, pa);                                                    \
        pb += STRIDE; pa += STRIDE;                                      \
    } while (0)

    // Prologue: 4 stages in flight (vmcnt = 8).
    ISSUE(0, x0); ISSUE(1, x1); ISSUE(2, x2); ISSUE(3, x3);

    f4v y;
    // Steady state: wait oldest stage, read this wave's own LDS slot (no
    // cross-wave sharing -> no barrier), drain ds_read before slot reuse,
    // refill, compute.
    WAITV(6); y = sB[0][threadIdx.x]; WAITLGKM(); ISSUE(0, x4); CP(x0, y);
    WAITV(6); y = sB[1][threadIdx.x]; WAITLGKM(); ISSUE(1, x5); CP(x1, y);
    WAITV(6); y = sB[2][threadIdx.x]; WAITLGKM(); ISSUE(2, x6); CP(x2, y);
    WAITV(6); y = sB[3][threadIdx.x]; WAITLGKM(); ISSUE(3, x7); CP(x3, y);
    // Drain.
    WAITV(6); y = sB[0][threadIdx.x]; CP(x4, y);
    WAITV(4); y = sB[1][threadIdx.x]; CP(x5, y);
    WAITV(2); y = sB[2][threadIdx.x]; CP(x6, y);
    WAITV(0); y = sB[3][threadIdx.x]; CP(x7, y);

    float acc = (acc0 + acc1) + (acc2 + acc3);

    // Wave-64 shuffle reduction (identical tree to baseline).
    #pragma unroll
    for (int off = 32; off > 0; off >>= 1)
        acc += __shfl_down(acc, off, 64);

    __shared__ float wave_sums[BLOCK / 64];
    int lane = threadIdx.x & 63;
    int wid  = threadIdx.x >> 6;
    if (lane == 0) wave_sums[wid] = acc;
    __syncthreads();

    if (threadIdx.x == 0) {
        float s = wave_sums[0] + wave_sums[1] + wave_sums[2] + wave_sums[3];
        partials[blockIdx.x] = s;  // deterministic: no atomics
    }
}

__global__ __launch_bounds__(BLOCK) void cep_final_kernel(
        const float* __restrict__ partials, float* __restrict__ out, int nparts) {
    float acc = 0.0f;
    for (int i = threadIdx.x; i < nparts; i += BLOCK)
        acc += partials[i];

    #pragma unroll
    for (int off = 32; off > 0; off >>= 1)
        acc += __shfl_down(acc, off, 64);

    __shared__ float wave_sums[BLOCK / 64];
    int lane = threadIdx.x & 63;
    int wid  = threadIdx.x >> 6;
    if (lane == 0) wave_sums[wid] = acc;
    __syncthreads();

    if (threadIdx.x == 0) {
        float s = wave_sums[0] + wave_sums[1] + wave_sums[2] + wave_sums[3];
        out[0] = -s;
    }
}

extern "C" void kernel_launch(void* const* d_in, const int* in_sizes, int n_in,
                              void* d_out, int out_size, void* d_ws, size_t ws_size,
                              hipStream_t stream) {
    const f4v* d1 = (const f4v*)d_in[0];
    const f4v* d2 = (const f4v*)d_in[1];
    float* out      = (float*)d_out;
    float* partials = (float*)d_ws;

    // n = 4096*4096 floats -> n4 = 4,194,304 float4. GRID*BLOCK*8 == n4.
    cep_loss_kernel<<<GRID, BLOCK, 0, stream>>>(d1, d2, partials);
    cep_final_kernel<<<1, BLOCK, 0, stream>>>(partials, out, GRID);
}

// Round 8
// 133.059 us; speedup vs baseline: 1.0650x; 1.0650x over previous
//
#include <hip/hip_runtime.h>
#include <math.h>

// loss = -sum_ij d1[i,j] * log(d2[i,j] + 1e-5), fp32 in, scalar fp32 out.
//
// Session ledger (loss-kernel us):
//   R0 43.4 baseline | R2 44.9 (8-deep VGPR pipe: null -> not MLP-bound)
//   R3 37.7 (d1 sc0sc1nt) | R4 31.0 (split read-return paths)  <- BEST
//   R5 39.6 (d2 aux=19: bad) | R6 34.0 (write-once slots: -3 vs ring)
//   R7 39.7 (NT-only both streams: bad)
// Confirmed mechanisms:
//  - Asymmetric path split is the optimum: d1 pinned to the HBM-direct
//    VGPR-return path (sc0 sc1 nt), d2 default-policy via global_load_lds
//    (TA->LDS return path, cache-served). Aggregate 268 MB / 31 us =
//    8.65 TB/s demand BW > 6.6 TB/s single-direction fill ceiling ->
//    the two paths are genuinely parallel (~4.3 TB/s each).
//  - ANY non-default aux on the LDS stream loses cache hits (R5/R6/R7:
//    aux=19 and aux=2 both +6..9 us). NT on this memory-side cache
//    behaves like demote/bypass, not "no-allocate but still hit".
//  - d1 flags win only as the full sc0 sc1 nt combo (R7: nt-only bad).
//  - Ring-4 @ 16 KB/block (8 blocks/CU, 32 waves/CU) > write-once-8 @
//    32 KB (5 blocks/CU): TLP beats per-wave depth (R2, R6).
//  - Reduction tree FROZEN (absmax 0.0): thread t owns t + p*STRIDE
//    p=0..7, per-component acc, wave shuffle, 4-wave LDS combine,
//    partials[blockIdx], 1-block final. Do not touch.
// R8: byte-exact restoration of R4 (current tree holds R7 = 8.7 us worse).
//     If ~133 us / ~31 us confirms, declare plateau: all single-variable
//     neighbors of this config have been measured worse.

#define EPS 1e-5f
#define BLOCK 256
#define GRID 2048                 // GRID*BLOCK*8 == n4 exactly
#define STRIDE (GRID * BLOCK)     // float4 stride between a thread's windows

typedef float f4v __attribute__((ext_vector_type(4)));

#define AS1 __attribute__((address_space(1)))
#define AS3 __attribute__((address_space(3)))

// d1 load on the VGPR-return path, L2-bypass + non-temporal (R3/R4 win).
#define LOADX(X, PA)                                                 \
    asm volatile("global_load_dwordx4 %0, %1, off sc0 sc1 nt"        \
                 : "=&v"(X) : "v"(PA) : "memory")

// Hand-counted vmem wait + scheduling fence (rule #18).
#define WAITV(N)                                              \
    do {                                                      \
        asm volatile("s_waitcnt vmcnt(" #N ")" ::: "memory"); \
        __builtin_amdgcn_sched_barrier(0);                    \
    } while (0)

// Drain LDS reads before ring-slot reuse.
#define WAITLGKM()                                              \
    do {                                                        \
        asm volatile("s_waitcnt lgkmcnt(0)" ::: "memory");      \
        __builtin_amdgcn_sched_barrier(0);                      \
    } while (0)

// Same element->acc mapping and fma contraction as the baseline.
#define CP(X, Y)                                              \
    do {                                                      \
        acc0 = fmaf((X).x, __logf((Y).x + EPS), acc0);        \
        acc1 = fmaf((X).y, __logf((Y).y + EPS), acc1);        \
        acc2 = fmaf((X).z, __logf((Y).z + EPS), acc2);        \
        acc3 = fmaf((X).w, __logf((Y).w + EPS), acc3);        \
    } while (0)

__global__ __launch_bounds__(BLOCK) void cep_loss_kernel(
        const f4v* __restrict__ d1,
        const f4v* __restrict__ d2,
        float* __restrict__ partials) {
    // 4-deep ring: 4 x 256 x 16B = 16 KB/block -> 8 blocks/CU = 32 waves/CU.
    __shared__ f4v sB[4][BLOCK];

    const int tid = blockIdx.x * BLOCK + threadIdx.x;
    const int wb  = threadIdx.x & ~63;   // wave-uniform LDS slot base
    const f4v* pa = d1 + tid;
    const f4v* pb = d2 + tid;

    float acc0 = 0.0f, acc1 = 0.0f, acc2 = 0.0f, acc3 = 0.0f;
    f4v x0, x1, x2, x3, x4, x5, x6, x7;

    // One stage: d2 -> LDS-direct with DEFAULT policy (aux=0: cache-served);
    // d1 -> VGPR path with sc0 sc1 nt (HBM-direct). 2 vmcnt ops/stage.
#define ISSUE(BUF, X)                                                    \
    do {                                                                 \
        __builtin_amdgcn_global_load_lds(                                \
            (const AS1 void*)pb, (AS3 void*)&sB[BUF][wb], 16, 0, 0);     \
        LOADX(X, pa);                                                    \
        pb += STRIDE; pa += STRIDE;                                      \
    } while (0)

    // Prologue: 4 stages in flight (vmcnt = 8).
    ISSUE(0, x0); ISSUE(1, x1); ISSUE(2, x2); ISSUE(3, x3);

    f4v y;
    // Steady state: wait oldest stage (2 ops), read this wave's own LDS
    // slot (no cross-wave sharing -> no barrier), drain ds_read before
    // slot reuse, refill, compute.
    WAITV(6); y = sB[0][threadIdx.x]; WAITLGKM(); ISSUE(0, x4); CP(x0, y);
    WAITV(6); y = sB[1][threadIdx.x]; WAITLGKM(); ISSUE(1, x5); CP(x1, y);
    WAITV(6); y = sB[2][threadIdx.x]; WAITLGKM(); ISSUE(2, x6); CP(x2, y);
    WAITV(6); y = sB[3][threadIdx.x]; WAITLGKM(); ISSUE(3, x7); CP(x3, y);
    // Drain.
    WAITV(6); y = sB[0][threadIdx.x]; CP(x4, y);
    WAITV(4); y = sB[1][threadIdx.x]; CP(x5, y);
    WAITV(2); y = sB[2][threadIdx.x]; CP(x6, y);
    WAITV(0); y = sB[3][threadIdx.x]; CP(x7, y);

    float acc = (acc0 + acc1) + (acc2 + acc3);

    // Wave-64 shuffle reduction (identical tree to baseline).
    #pragma unroll
    for (int off = 32; off > 0; off >>= 1)
        acc += __shfl_down(acc, off, 64);

    __shared__ float wave_sums[BLOCK / 64];
    int lane = threadIdx.x & 63;
    int wid  = threadIdx.x >> 6;
    if (lane == 0) wave_sums[wid] = acc;
    __syncthreads();

    if (threadIdx.x == 0) {
        float s = wave_sums[0] + wave_sums[1] + wave_sums[2] + wave_sums[3];
        partials[blockIdx.x] = s;  // deterministic: no atomics
    }
}

__global__ __launch_bounds__(BLOCK) void cep_final_kernel(
        const float* __restrict__ partials, float* __restrict__ out, int nparts) {
    float acc = 0.0f;
    for (int i = threadIdx.x; i < nparts; i += BLOCK)
        acc += partials[i];

    #pragma unroll
    for (int off = 32; off > 0; off >>= 1)
        acc += __shfl_down(acc, off, 64);

    __shared__ float wave_sums[BLOCK / 64];
    int lane = threadIdx.x & 63;
    int wid  = threadIdx.x >> 6;
    if (lane == 0) wave_sums[wid] = acc;
    __syncthreads();

    if (threadIdx.x == 0) {
        float s = wave_sums[0] + wave_sums[1] + wave_sums[2] + wave_sums[3];
        out[0] = -s;
    }
}

extern "C" void kernel_launch(void* const* d_in, const int* in_sizes, int n_in,
                              void* d_out, int out_size, void* d_ws, size_t ws_size,
                              hipStream_t stream) {
    const f4v* d1 = (const f4v*)d_in[0];
    const f4v* d2 = (const f4v*)d_in[1];
    float* out      = (float*)d_out;
    float* partials = (float*)d_ws;

    // n = 4096*4096 floats -> n4 = 4,194,304 float4. GRID*BLOCK*8 == n4.
    cep_loss_kernel<<<GRID, BLOCK, 0, stream>>>(d1, d2, partials);
    cep_final_kernel<<<1, BLOCK, 0, stream>>>(partials, out, GRID);
}

// Round 9
// 131.283 us; speedup vs baseline: 1.0794x; 1.0135x over previous
//
#include <hip/hip_runtime.h>
#include <math.h>

// loss = -sum_ij d1[i,j] * log(d2[i,j] + 1e-5), fp32 in, scalar fp32 out.
//
// Session ledger (loss-kernel us):
//   R0 43.4 | R2 44.9 (8-deep VGPR pipe: null) | R3 37.7 (d1 sc0sc1nt)
//   R4 31.0 (path split: d2 LDS-direct aux0, d1 VGPR bypass)  <- BEST
//   R5 39.6 (d2 aux19) | R6 34.0 (write-once, 5 blk/CU) | R7 39.7 (NT-only)
//   R8 133.1 harness re-confirm of R4 (~31 us).
// Confirmed mechanisms:
//  - Asymmetric path split optimal; any non-default aux on the LDS stream
//    loses cache hits; d1 flags win only as full sc0 sc1 nt.
//  - Ring-4 @16KB (8 blk/CU, 32 waves) > write-once @32KB (5 blk/CU).
//  - Per-path rates: VGPR path ~3.6 TB/s (R3), so in R4 it finishes its
//    67 MB in ~19 us and idles; d2/LDS path is the straggler (~2.2 TB/s).
//    Candidate cause: per-stage s_waitcnt lgkmcnt(0) full drain (~120cy,
//    serial) guarding slot reuse in the same stage as the ds_read.
//  - Reduction tree FROZEN (absmax 0.0): thread t owns t + p*STRIDE p=0..7,
//    per-component acc, wave shuffle, 4-wave LDS combine, partials[blk].
// R9: pipeline ds_reads one stage AHEAD of slot reuse. All LDS reads are
//     explicit asm ds_read_b128 (lgkm fully hand-counted); guard becomes
//     lgkmcnt(1) on a read issued a full stage earlier (~free). Everything
//     else byte-identical to R8. Null result => LDS-path service ceiling
//     => roofline declaration next round.

#define EPS 1e-5f
#define BLOCK 256
#define GRID 2048                 // GRID*BLOCK*8 == n4 exactly
#define STRIDE (GRID * BLOCK)     // float4 stride between a thread's windows

typedef float f4v __attribute__((ext_vector_type(4)));

#define AS1 __attribute__((address_space(1)))
#define AS3 __attribute__((address_space(3)))

// d1 load on the VGPR-return path, L2-bypass + non-temporal (R3/R4 win).
#define LOADX(X, PA)                                                 \
    asm volatile("global_load_dwordx4 %0, %1, off sc0 sc1 nt"        \
                 : "=&v"(X) : "v"(PA) : "memory")

// Explicit LDS read: lgkm counting is fully ours (DS ops retire in order).
#define DSR(Y, P)                                                    \
    asm volatile("ds_read_b128 %0, %1"                               \
                 : "=&v"(Y)                                          \
                 : "v"((unsigned)(size_t)(AS3 void*)&sB[P][threadIdx.x]) \
                 : "memory")

// Hand-counted vmem wait + scheduling fence (rule #18).
#define WAITV(N)                                              \
    do {                                                      \
        asm volatile("s_waitcnt vmcnt(" #N ")" ::: "memory"); \
        __builtin_amdgcn_sched_barrier(0);                    \
    } while (0)

// Hand-counted LDS wait + scheduling fence (rule #18: without the
// sched_barrier, register-only consumers can hoist past the asm wait).
#define WAITL(N)                                                \
    do {                                                        \
        asm volatile("s_waitcnt lgkmcnt(" #N ")" ::: "memory"); \
        __builtin_amdgcn_sched_barrier(0);                      \
    } while (0)

// Same element->acc mapping and fma contraction as the baseline.
#define CP(X, Y)                                              \
    do {                                                      \
        acc0 = fmaf((X).x, __logf((Y).x + EPS), acc0);        \
        acc1 = fmaf((X).y, __logf((Y).y + EPS), acc1);        \
        acc2 = fmaf((X).z, __logf((Y).z + EPS), acc2);        \
        acc3 = fmaf((X).w, __logf((Y).w + EPS), acc3);        \
    } while (0)

__global__ __launch_bounds__(BLOCK) void cep_loss_kernel(
        const f4v* __restrict__ d1,
        const f4v* __restrict__ d2,
        float* __restrict__ partials) {
    // 4-deep ring: 4 x 256 x 16B = 16 KB/block -> 8 blocks/CU = 32 waves/CU.
    __shared__ f4v sB[4][BLOCK];

    const int tid = blockIdx.x * BLOCK + threadIdx.x;
    const int wb  = threadIdx.x & ~63;   // wave-uniform LDS slot base
    const f4v* pa = d1 + tid;
    const f4v* pb = d2 + tid;

    float acc0 = 0.0f, acc1 = 0.0f, acc2 = 0.0f, acc3 = 0.0f;
    f4v x0, x1, x2, x3, x4, x5, x6, x7;
    f4v r0, r1, r2, r3, r4, r5, r6, r7;

    // One stage: d2 -> LDS-direct DEFAULT policy (cache-served);
    // d1 -> VGPR path sc0 sc1 nt (HBM-direct). 2 vmcnt ops/stage.
#define ISSUE(BUF, X)                                                    \
    do {                                                                 \
        __builtin_amdgcn_global_load_lds(                                \
            (const AS1 void*)pb, (AS3 void*)&sB[BUF][wb], 16, 0, 0);     \
        LOADX(X, pa);                                                    \
        pb += STRIDE; pa += STRIDE;                                      \
    } while (0)

    // Prologue: 4 stages in flight (vmcnt = 8).
    ISSUE(0, x0); ISSUE(1, x1); ISSUE(2, x2); ISSUE(3, x3);

    // Read-ahead prologue: slot0 and slot1 ds_reads issued before any reuse.
    WAITV(6); DSR(r0, 0);                       // lgkm: {r0}
    WAITV(4); DSR(r1, 1);                       // lgkm: {r0,r1}
    // Steady state: guard slot reuse with lgkmcnt(1) on a read issued a
    // full stage earlier (in-order DS retire => oldest is done). Keep
    // reading one slot ahead of the reissue.
    WAITL(1); ISSUE(0, x4); CP(x0, r0);         // slot0 reused; r1 pending
    WAITV(4); DSR(r2, 2);
    WAITL(1); ISSUE(1, x5); CP(x1, r1);
    WAITV(4); DSR(r3, 3);
    WAITL(1); ISSUE(2, x6); CP(x2, r2);
    WAITV(4); DSR(r4, 0);                       // slot0, second generation
    WAITL(1); ISSUE(3, x7); CP(x3, r3);
    // Drain: no more reissues, just read-ahead + compute.
    WAITV(4); DSR(r5, 1);
    WAITL(1); CP(x4, r4);
    WAITV(2); DSR(r6, 2);
    WAITL(1); CP(x5, r5);
    WAITV(0); DSR(r7, 3);
    WAITL(1); CP(x6, r6);
    WAITL(0); CP(x7, r7);

    float acc = (acc0 + acc1) + (acc2 + acc3);

    // Wave-64 shuffle reduction (identical tree to baseline).
    #pragma unroll
    for (int off = 32; off > 0; off >>= 1)
        acc += __shfl_down(acc, off, 64);

    __shared__ float wave_sums[BLOCK / 64];
    int lane = threadIdx.x & 63;
    int wid  = threadIdx.x >> 6;
    if (lane == 0) wave_sums[wid] = acc;
    __syncthreads();

    if (threadIdx.x == 0) {
        float s = wave_sums[0] + wave_sums[1] + wave_sums[2] + wave_sums[3];
        partials[blockIdx.x] = s;  // deterministic: no atomics
    }
}

__global__ __launch_bounds__(BLOCK) void cep_final_kernel(
        const float* __restrict__ partials, float* __restrict__ out, int nparts) {
    float acc = 0.0f;
    for (int i = threadIdx.x; i < nparts; i += BLOCK)
        acc += partials[i];

    #pragma unroll
    for (int off = 32; off > 0; off >>= 1)
        acc += __shfl_down(acc, off, 64);

    __shared__ float wave_sums[BLOCK / 64];
    int lane = threadIdx.x & 63;
    int wid  = threadIdx.x >> 6;
    if (lane == 0) wave_sums[wid] = acc;
    __syncthreads();

    if (threadIdx.x == 0) {
        float s = wave_sums[0] + wave_sums[1] + wave_sums[2] + wave_sums[3];
        out[0] = -s;
    }
}

extern "C" void kernel_launch(void* const* d_in, const int* in_sizes, int n_in,
                              void* d_out, int out_size, void* d_ws, size_t ws_size,
                              hipStream_t stream) {
    const f4v* d1 = (const f4v*)d_in[0];
    const f4v* d2 = (const f4v*)d_in[1];
    float* out      = (float*)d_out;
    float* partials = (float*)d_ws;

    // n = 4096*4096 floats -> n4 = 4,194,304 float4. GRID*BLOCK*8 == n4.
    cep_loss_kernel<<<GRID, BLOCK, 0, stream>>>(d1, d2, partials);
    cep_final_kernel<<<1, BLOCK, 0, stream>>>(partials, out, GRID);
}